// Round 1
// baseline (371.948 us; speedup 1.0000x reference)
//
#include <hip/hip_runtime.h>
#include <hip/hip_bf16.h>

// InteractionBlock: B=16,N=192,H=128,F=128,G=50
//   fw  = softplus(rbf@W1+b1)@W2+b2          [B,N,N,F]   (never materialized)
//   nf  = features@Wf+bf                      [B,N,F]
//   agg = sum_j mask[b,i,j]*fw[b,i,j,:]*nf[b,j,:]
//   out = features + softplus(agg@Wo1+bo1)@Wo2+bo2
//
// v2 changes vs previous session kernel:
//  - main: per-block compaction of active neighbor rows (mask ~50% dense) ->
//    GEMM1/softplus/GEMM2/epilogue all scale with nm (~96) not 192.
//  - main: rbf A-frags via 4 dword loads (row = exactly 25 dwords), predicate
//    only on the second K-step; no per-element bounds checks.
//  - main: s_hs pitch 136 -> 128 + XOR swizzle (byte ^= (row&7)<<4):
//    LDS 53.8KB -> 50.4KB -> 3 blocks/CU (occupancy 22% -> ~33%).
//  - nf/out rewritten as MFMA GEMM kernels (were 128-deep serial scalar FMA
//    chains, suspected ~170us combined). out keeps fp32-accuracy on agg via
//    bf16 hi/lo split (2 MFMAs per K-step).

typedef __bf16 bf16_t;
typedef __bf16 bf16x8 __attribute__((ext_vector_type(8)));
typedef float  f32x4  __attribute__((ext_vector_type(4)));
typedef unsigned int uintx4 __attribute__((ext_vector_type(4)));

constexpr int kB = 16, kN = 192, kH = 128, kF = 128, kG = 50;
constexpr int kRows = kB * kN;        // 3072
constexpr int kOutPitch = 136;        // bf16 elems, mult of 8 -> aligned b128

__device__ __forceinline__ float ldf(const void* p, int i, bool bfm) {
  return bfm ? (float)((const bf16_t*)p)[i] : ((const float*)p)[i];
}

__device__ __forceinline__ float softplus_f(float x) {
  float t = __logf(1.f + __expf(fminf(x, 20.f)));
  return x > 20.f ? x : t;
}

// ---- dtype detector: flag=1 if inputs are packed bf16, 0 if fp32 ----
__global__ __launch_bounds__(256) void detect_kernel(const unsigned int* __restrict__ rbf_w,
                                                     int* __restrict__ flag) {
  __shared__ int c_hi, c_zero;
  const int t = threadIdx.x;
  if (t == 0) { c_hi = 0; c_zero = 0; }
  __syncthreads();
  unsigned int w = rbf_w[(size_t)t * 40003u];   // in-bounds for both dtypes
  unsigned int lo = w & 0xFFFFu;
  if (((lo >> 7) & 0xFFu) >= 128u) atomicAdd(&c_hi, 1);   // |bf16| >= 2: impossible for rbf in [0,1)
  if (lo == 0u) atomicAdd(&c_zero, 1);
  __syncthreads();
  if (t == 0) *flag = (c_hi == 0 && c_zero < 200) ? 1 : 0;
}

// ---- transpose all weight matrices into bf16 [n][k] ----
// w1t: [128][64] (G padded 50->64), w2t/wft/wo1t/wo2t: [128][128]
__global__ __launch_bounds__(256) void prep_kernel(
    const void* __restrict__ W1, const void* __restrict__ W2,
    const void* __restrict__ Wf, const void* __restrict__ Wo1,
    const void* __restrict__ Wo2, const int* __restrict__ flag,
    bf16_t* __restrict__ w1t, bf16_t* __restrict__ w2t,
    bf16_t* __restrict__ wft, bf16_t* __restrict__ wo1t,
    bf16_t* __restrict__ wo2t) {
  const bool bfm = *flag != 0;
  int idx = blockIdx.x * 256 + threadIdx.x;
  if (idx < 8192) {                       // w1t
    int n = idx >> 6, k = idx & 63;
    w1t[idx] = (k < kG) ? (bf16_t)ldf(W1, k * kF + n, bfm) : (bf16_t)0.f;
  } else if (idx < 8192 + 16384) {        // w2t
    int i2 = idx - 8192; int n = i2 >> 7, k = i2 & 127;
    w2t[i2] = (bf16_t)ldf(W2, k * kF + n, bfm);
  } else if (idx < 8192 + 2 * 16384) {    // wft
    int i2 = idx - 8192 - 16384; int n = i2 >> 7, k = i2 & 127;
    wft[i2] = (bf16_t)ldf(Wf, k * kF + n, bfm);
  } else if (idx < 8192 + 3 * 16384) {    // wo1t
    int i2 = idx - 8192 - 2 * 16384; int n = i2 >> 7, k = i2 & 127;
    wo1t[i2] = (bf16_t)ldf(Wo1, k * kH + n, bfm);
  } else if (idx < 8192 + 4 * 16384) {    // wo2t
    int i2 = idx - 8192 - 3 * 16384; int n = i2 >> 7, k = i2 & 127;
    wo2t[i2] = (bf16_t)ldf(Wo2, k * kH + n, bfm);
  }
}

// ---- nf = features @ Wf + bf  (MFMA; fp32 result) ----
// grid 96, block 128 (2 waves x 16 rows)
__global__ __launch_bounds__(128) void nf_kernel(const void* __restrict__ features,
                                                 const bf16_t* __restrict__ wft,
                                                 const void* __restrict__ bfv,
                                                 const int* __restrict__ flag,
                                                 float* __restrict__ nf) {
  const bool bfm = *flag != 0;
  const int t = threadIdx.x, wave = t >> 6, lane = t & 63;
  const int n16 = lane & 15, q = lane >> 4;
  const int rbase = blockIdx.x * 32 + wave * 16;
  const int arow = rbase + n16;

  f32x4 acc[8];
#pragma unroll
  for (int nt = 0; nt < 8; ++nt)
#pragma unroll
    for (int r = 0; r < 4; ++r) acc[nt][r] = 0.f;

  if (bfm) {
    const bf16_t* fp = (const bf16_t*)features + (size_t)arow * kH;
#pragma unroll
    for (int ks = 0; ks < 4; ++ks) {
      bf16x8 afr = *(const bf16x8*)(fp + ks * 32 + q * 8);
#pragma unroll
      for (int nt = 0; nt < 8; ++nt) {
        bf16x8 bfr = *(const bf16x8*)(wft + (nt * 16 + n16) * kH + ks * 32 + q * 8);
        acc[nt] = __builtin_amdgcn_mfma_f32_16x16x32_bf16(afr, bfr, acc[nt], 0, 0, 0);
      }
    }
  } else {
    const float* fp = (const float*)features + (size_t)arow * kH;
#pragma unroll
    for (int ks = 0; ks < 4; ++ks) {
      f32x4 x0 = *(const f32x4*)(fp + ks * 32 + q * 8);
      f32x4 x1 = *(const f32x4*)(fp + ks * 32 + q * 8 + 4);
      bf16x8 ahi, alo;
#pragma unroll
      for (int e = 0; e < 4; ++e) {
        bf16_t h0 = (bf16_t)x0[e]; ahi[e]     = h0; alo[e]     = (bf16_t)(x0[e] - (float)h0);
        bf16_t h1 = (bf16_t)x1[e]; ahi[e + 4] = h1; alo[e + 4] = (bf16_t)(x1[e] - (float)h1);
      }
#pragma unroll
      for (int nt = 0; nt < 8; ++nt) {
        bf16x8 bfr = *(const bf16x8*)(wft + (nt * 16 + n16) * kH + ks * 32 + q * 8);
        acc[nt] = __builtin_amdgcn_mfma_f32_16x16x32_bf16(ahi, bfr, acc[nt], 0, 0, 0);
        acc[nt] = __builtin_amdgcn_mfma_f32_16x16x32_bf16(alo, bfr, acc[nt], 0, 0, 0);
      }
    }
  }
  // C layout: col = lane&15, row = q*4 + r
#pragma unroll
  for (int nt = 0; nt < 8; ++nt) {
    const int col = nt * 16 + n16;
    const float bv = ldf(bfv, col, bfm);
#pragma unroll
    for (int r = 0; r < 4; ++r)
      nf[(size_t)(rbase + q * 4 + r) * kF + col] = acc[nt][r] + bv;
  }
}

// ---- main: per (b,i): compact active rows -> GEMM1 -> softplus -> LDS ->
// ----       GEMM2 -> masked-free reduce (mask folded into compaction) ----
__global__ __launch_bounds__(256, 3) void main_kernel(
    const void* __restrict__ rbf, const int* __restrict__ nmask,
    const void* __restrict__ b1p, const void* __restrict__ b2p,
    const bf16_t* __restrict__ w1t, const bf16_t* __restrict__ w2t,
    const float* __restrict__ nf, const int* __restrict__ flag,
    float* __restrict__ agg) {
  __shared__ bf16_t s_hs[kN * 128];     // 49152 B, XOR-swizzled (byte ^= (row&7)<<4)
  __shared__ int    s_rows[kN];
  __shared__ float  s_agg[kF];
  __shared__ int    s_cnt;

  const bool bfm = *flag != 0;
  const int bi = blockIdx.x;
  const int b  = bi / kN;
  const int t  = threadIdx.x;
  const int wave = t >> 6, lane = t & 63;
  const int n16 = lane & 15, q = lane >> 4;

  if (t == 0) s_cnt = 0;
  if (t < kF) s_agg[t] = 0.f;
  __syncthreads();
  for (int j = t; j < kN; j += 256)
    if (nmask[bi * kN + j] != 0) s_rows[atomicAdd(&s_cnt, 1)] = j;
  __syncthreads();
  const int nm = s_cnt;
  const int ntiles = (nm + 15) >> 4;
  for (int p2 = nm + t; p2 < ntiles * 16; p2 += 256) s_rows[p2] = 0;  // pad: dup row 0, weight 0
  __syncthreads();

  float b1r[8], b2r[8];
#pragma unroll
  for (int nt = 0; nt < 8; ++nt) {
    b1r[nt] = ldf(b1p, nt * 16 + n16, bfm);
    b2r[nt] = ldf(b2p, nt * 16 + n16, bfm);
  }

  char* hsb = (char*)s_hs;

  // ---- phase 1: GEMM1 (rbf[act,50->64] @ W1) + softplus -> s_hs ----
  for (int tt = wave; tt < ntiles; tt += 4) {
    const int j = s_rows[tt * 16 + n16];
    bf16x8 a0, a1;
    if (bfm) {
      // rbf row = exactly 25 dwords (50 bf16). ks=0 dwords q*4+i in [0,19]:
      // always valid; ks=1 dwords 16+q*4+i: predicate d<25.
      const unsigned int* rp = (const unsigned int*)rbf + (size_t)bi * 4800 + j * 25;
      uintx4 u0, u1;
#pragma unroll
      for (int i = 0; i < 4; ++i) u0[i] = rp[q * 4 + i];
#pragma unroll
      for (int i = 0; i < 4; ++i) {
        const int d = 16 + q * 4 + i;
        u1[i] = (d < 25) ? rp[d] : 0u;
      }
      a0 = __builtin_bit_cast(bf16x8, u0);
      a1 = __builtin_bit_cast(bf16x8, u1);
    } else {
      const float* rp = (const float*)rbf + (size_t)bi * (kN * kG) + j * kG;
#pragma unroll
      for (int i = 0; i < 8; ++i) a0[i] = (bf16_t)rp[q * 8 + i];          // k<=31<50
#pragma unroll
      for (int i = 0; i < 8; ++i) {
        const int k1 = 32 + q * 8 + i;
        a1[i] = (bf16_t)((k1 < kG) ? rp[k1] : 0.f);
      }
    }

    f32x4 acc1[8];
#pragma unroll
    for (int nt = 0; nt < 8; ++nt)
#pragma unroll
      for (int r = 0; r < 4; ++r) acc1[nt][r] = 0.f;

#pragma unroll
    for (int nt = 0; nt < 8; ++nt) {
      bf16x8 bf0 = *(const bf16x8*)(w1t + (nt * 16 + n16) * 64 + q * 8);
      acc1[nt] = __builtin_amdgcn_mfma_f32_16x16x32_bf16(a0, bf0, acc1[nt], 0, 0, 0);
    }
#pragma unroll
    for (int nt = 0; nt < 8; ++nt) {
      bf16x8 bf1 = *(const bf16x8*)(w1t + (nt * 16 + n16) * 64 + 32 + q * 8);
      acc1[nt] = __builtin_amdgcn_mfma_f32_16x16x32_bf16(a1, bf1, acc1[nt], 0, 0, 0);
    }

    // bias + softplus -> s_hs (swizzled). C layout: col = lane&15, row = q*4+r.
#pragma unroll
    for (int nt = 0; nt < 8; ++nt) {
      const int colb = (nt * 16 + n16) * 2;
#pragma unroll
      for (int r = 0; r < 4; ++r) {
        const int row = tt * 16 + q * 4 + r;
        *(bf16_t*)(hsb + ((row * 256 + colb) ^ ((row & 7) << 4))) =
            (bf16_t)softplus_f(acc1[nt][r] + b1r[nt]);
      }
    }
  }
  __syncthreads();

  // ---- phase 2: GEMM2 (Hs[act,128] @ W2) + fused reduce into s_agg ----
  for (int tt = wave; tt < ntiles; tt += 4) {
    f32x4 acc2[8];
#pragma unroll
    for (int nt = 0; nt < 8; ++nt)
#pragma unroll
      for (int r = 0; r < 4; ++r) acc2[nt][r] = 0.f;

#pragma unroll
    for (int ks = 0; ks < 4; ++ks) {
      const int row = tt * 16 + n16;
      bf16x8 afr = *(const bf16x8*)(hsb +
          ((row * 256 + (ks * 32 + q * 8) * 2) ^ ((row & 7) << 4)));
#pragma unroll
      for (int nt = 0; nt < 8; ++nt) {
        bf16x8 bfr = *(const bf16x8*)(w2t + (nt * 16 + n16) * 128 + ks * 32 + q * 8);
        acc2[nt] = __builtin_amdgcn_mfma_f32_16x16x32_bf16(afr, bfr, acc2[nt], 0, 0, 0);
      }
    }

    const int i0 = tt * 16 + q * 4;
    int jr[4]; float wr[4];
#pragma unroll
    for (int r = 0; r < 4; ++r) {
      const int idx = i0 + r;
      jr[r] = s_rows[idx];
      wr[r] = (idx < nm) ? 1.f : 0.f;
    }
    const float* nfb = nf + (size_t)b * kN * kF;
#pragma unroll
    for (int nt = 0; nt < 8; ++nt) {
      const int f = nt * 16 + n16;
      float p = 0.f;
#pragma unroll
      for (int r = 0; r < 4; ++r)
        p = fmaf(wr[r] * (acc2[nt][r] + b2r[nt]), nfb[jr[r] * kF + f], p);
      atomicAdd(&s_agg[f], p);
    }
  }
  __syncthreads();
  if (t < kF) agg[(size_t)bi * kF + t] = s_agg[t];
}

// ---- out = features + softplus(agg@Wo1+bo1)@Wo2+bo2  (MFMA, hi/lo-split agg) ----
// grid 96, block 128 (2 waves x 16 rows)
__global__ __launch_bounds__(128) void out_kernel(
    const float* __restrict__ agg, const void* __restrict__ features,
    const bf16_t* __restrict__ wo1t, const bf16_t* __restrict__ wo2t,
    const void* __restrict__ bo1, const void* __restrict__ bo2,
    const int* __restrict__ flag, void* __restrict__ out) {
  __shared__ bf16_t s_t[32 * kOutPitch];   // 8704 B
  const bool bfm = *flag != 0;
  const int t = threadIdx.x, wave = t >> 6, lane = t & 63;
  const int n16 = lane & 15, q = lane >> 4;
  const int rb = blockIdx.x * 32 + wave * 16;

  f32x4 acc[8];
#pragma unroll
  for (int nt = 0; nt < 8; ++nt)
#pragma unroll
    for (int r = 0; r < 4; ++r) acc[nt][r] = 0.f;

  // GEMM-a: A = agg rows in bf16 hi/lo split (keeps fp32-level accuracy)
  const float* ap = agg + (size_t)(rb + n16) * kF;
#pragma unroll
  for (int ks = 0; ks < 4; ++ks) {
    f32x4 x0 = *(const f32x4*)(ap + ks * 32 + q * 8);
    f32x4 x1 = *(const f32x4*)(ap + ks * 32 + q * 8 + 4);
    bf16x8 ahi, alo;
#pragma unroll
    for (int e = 0; e < 4; ++e) {
      bf16_t h0 = (bf16_t)x0[e]; ahi[e]     = h0; alo[e]     = (bf16_t)(x0[e] - (float)h0);
      bf16_t h1 = (bf16_t)x1[e]; ahi[e + 4] = h1; alo[e + 4] = (bf16_t)(x1[e] - (float)h1);
    }
#pragma unroll
    for (int nt = 0; nt < 8; ++nt) {
      bf16x8 bfr = *(const bf16x8*)(wo1t + (nt * 16 + n16) * kF + ks * 32 + q * 8);
      acc[nt] = __builtin_amdgcn_mfma_f32_16x16x32_bf16(ahi, bfr, acc[nt], 0, 0, 0);
      acc[nt] = __builtin_amdgcn_mfma_f32_16x16x32_bf16(alo, bfr, acc[nt], 0, 0, 0);
    }
  }
  // bias + softplus -> s_t (bf16)
#pragma unroll
  for (int nt = 0; nt < 8; ++nt) {
    const int col = nt * 16 + n16;
    const float bv = ldf(bo1, col, bfm);
#pragma unroll
    for (int r = 0; r < 4; ++r)
      s_t[(wave * 16 + q * 4 + r) * kOutPitch + col] = (bf16_t)softplus_f(acc[nt][r] + bv);
  }
  __syncthreads();

  // GEMM-b: hidden @ Wo2
#pragma unroll
  for (int nt = 0; nt < 8; ++nt)
#pragma unroll
    for (int r = 0; r < 4; ++r) acc[nt][r] = 0.f;
#pragma unroll
  for (int ks = 0; ks < 4; ++ks) {
    bf16x8 afr = *(const bf16x8*)(s_t + (wave * 16 + n16) * kOutPitch + ks * 32 + q * 8);
#pragma unroll
    for (int nt = 0; nt < 8; ++nt) {
      bf16x8 bfr = *(const bf16x8*)(wo2t + (nt * 16 + n16) * kH + ks * 32 + q * 8);
      acc[nt] = __builtin_amdgcn_mfma_f32_16x16x32_bf16(afr, bfr, acc[nt], 0, 0, 0);
    }
  }
  // + bo2 + residual, store
#pragma unroll
  for (int nt = 0; nt < 8; ++nt) {
    const int col = nt * 16 + n16;
    const float bv = ldf(bo2, col, bfm);
#pragma unroll
    for (int r = 0; r < 4; ++r) {
      const int row = rb + q * 4 + r;
      float res = ldf(features, (size_t)row * kH + col, bfm) + acc[nt][r] + bv;
      if (bfm) ((bf16_t*)out)[(size_t)row * kH + col] = (bf16_t)res;
      else     ((float*)out)[(size_t)row * kH + col]  = res;
    }
  }
}

extern "C" void kernel_launch(void* const* d_in, const int* in_sizes, int n_in,
                              void* d_out, int out_size, void* d_ws, size_t ws_size,
                              hipStream_t stream) {
  const void* features = d_in[0];
  const void* rbf      = d_in[1];
  const int*  nmask    = (const int*)d_in[2];
  const void* W1  = d_in[3];
  const void* b1  = d_in[4];
  const void* W2  = d_in[5];
  const void* b2  = d_in[6];
  const void* Wf  = d_in[7];
  const void* bfv = d_in[8];
  const void* Wo1 = d_in[9];
  const void* bo1 = d_in[10];
  const void* Wo2 = d_in[11];
  const void* bo2 = d_in[12];

  char* ws = (char*)d_ws;
  float*  nf   = (float*)ws;                   // 3072*128 f32 = 1,572,864 B
  float*  agg  = (float*)(ws + 1572864);       // 1,572,864 B
  bf16_t* w1t  = (bf16_t*)(ws + 3145728);      // 128*64  bf16 = 16,384 B
  bf16_t* w2t  = (bf16_t*)(ws + 3162112);      // 128*128 bf16 = 32,768 B
  bf16_t* wft  = (bf16_t*)(ws + 3194880);      // 32,768 B
  bf16_t* wo1t = (bf16_t*)(ws + 3227648);      // 32,768 B
  bf16_t* wo2t = (bf16_t*)(ws + 3260416);      // 32,768 B
  int*    flag = (int*)(ws + 3293184);         // 4 B

  detect_kernel<<<1, 256, 0, stream>>>((const unsigned int*)rbf, flag);
  prep_kernel<<<288, 256, 0, stream>>>(W1, W2, Wf, Wo1, Wo2, flag, w1t, w2t, wft, wo1t, wo2t);
  nf_kernel<<<96, 128, 0, stream>>>(features, wft, bfv, flag, nf);
  main_kernel<<<kRows, 256, 0, stream>>>(rbf, nmask, b1, b2, w1t, w2t, nf, flag, agg);
  out_kernel<<<96, 128, 0, stream>>>(agg, features, wo1t, wo2t, bo1, bo2, flag, d_out);
}